// Round 8
// baseline (469.390 us; speedup 1.0000x reference)
//
#include <hip/hip_runtime.h>
#include <hip/hip_bf16.h>

#define IN_FEAT 128
#define N_HEADS 4
#define OUT_FEAT 16
#define HF 64  // N_HEADS * OUT_FEAT
#define NEG_SLOPE 0.2f

#define BSHIFT 7                 // 128 nodes per bucket
#define BNODES 128
#define NBUCK_MAX 512            // >= ceil(50000/128)=391
#define APAD 65                  // LDS acc row stride (64+1): decorrelates ds_add banks

typedef __hip_bfloat16 bf16;
typedef __attribute__((ext_vector_type(8))) short short8;
typedef __attribute__((ext_vector_type(4))) float f32x4;

__device__ inline unsigned short f2b(float f) {
  bf16 b = __float2bfloat16(f);
  return *(unsigned short*)&b;
}
__device__ inline float b2f(unsigned short u) {
  return __uint_as_float((unsigned)u << 16);
}

// ---------------------------------------------------------------------------
// Kernel 1: h = x @ W via bf16 MFMA + fused LDS bucket histogram (no global
// atomics). Block = 256 thr = 4 waves = 64 nodes. Histogram chunk = blockIdx;
// k_part uses the same chunk mapping.
// ---------------------------------------------------------------------------
__global__ __launch_bounds__(256) void k_gemm(
    const float* __restrict__ x, const float* __restrict__ W,
    const float* __restrict__ a, unsigned short* __restrict__ h16,
    float* __restrict__ e_src, float* __restrict__ e_dst,
    const int* __restrict__ dst, int* __restrict__ bh,
    int n_nodes, int n_edges, int nbuck, int chunkE, int gb) {
  __shared__ unsigned short xs[64][136];
  __shared__ unsigned short wt[64][136];
  __shared__ unsigned short sh[64][68];
  __shared__ int bhist[NBUCK_MAX];
  const int t = threadIdx.x;
  const int nb = blockIdx.x * 64;
  const int lane = t & 63;
  const int w = t >> 6;

  for (int i = t; i < NBUCK_MAX; i += 256) bhist[i] = 0;

  const float4* x4 = (const float4*)x;
  for (int i = t; i < 64 * 32; i += 256) {
    int n = i >> 5, k4 = i & 31;
    int gn = nb + n;
    float4 v = (gn < n_nodes) ? x4[(size_t)gn * 32 + k4]
                              : make_float4(0.f, 0.f, 0.f, 0.f);
    ushort4 u;
    u.x = f2b(v.x); u.y = f2b(v.y); u.z = f2b(v.z); u.w = f2b(v.w);
    *(ushort4*)&xs[n][k4 * 4] = u;
  }
  for (int i = t; i < IN_FEAT * HF; i += 256) {
    int k = i >> 6, c = i & 63;
    wt[c][k] = f2b(W[i]);
  }
  __syncthreads();

  const int m = lane & 15;
  const int q = lane >> 4;
  f32x4 acc[4];
#pragma unroll
  for (int nt = 0; nt < 4; ++nt) acc[nt] = (f32x4){0.f, 0.f, 0.f, 0.f};

#pragma unroll
  for (int kc = 0; kc < 4; ++kc) {
    short8 af = *(const short8*)&xs[w * 16 + m][kc * 32 + q * 8];
#pragma unroll
    for (int nt = 0; nt < 4; ++nt) {
      short8 bfr = *(const short8*)&wt[nt * 16 + m][kc * 32 + q * 8];
      acc[nt] = __builtin_amdgcn_mfma_f32_16x16x32_bf16(af, bfr, acc[nt], 0, 0, 0);
    }
  }

#pragma unroll
  for (int nt = 0; nt < 4; ++nt)
#pragma unroll
    for (int r = 0; r < 4; ++r)
      sh[w * 16 + q * 4 + r][nt * 16 + m] = f2b(acc[nt][r]);
  __syncthreads();

  {
    int n = t >> 2, hd = t & 3;
    int gn = nb + n;
    if (gn < n_nodes) {
      float es = 0.f, ed = 0.f;
#pragma unroll
      for (int f = 0; f < OUT_FEAT; ++f) {
        float hv = b2f(sh[n][hd * 16 + f]);
        es = fmaf(hv, a[hd * 2 * OUT_FEAT + f], es);
        ed = fmaf(hv, a[hd * 2 * OUT_FEAT + OUT_FEAT + f], ed);
      }
      e_src[gn * N_HEADS + hd] = es;
      e_dst[gn * N_HEADS + hd] = ed;
    }
  }

  for (int i = t; i < 64 * 16; i += 256) {
    int n = i >> 4, c4 = (i & 15) * 4;
    int gn = nb + n;
    if (gn < n_nodes) {
      ushort4 v;
      v.x = sh[n][c4 + 0]; v.y = sh[n][c4 + 1];
      v.z = sh[n][c4 + 2]; v.w = sh[n][c4 + 3];
      *(ushort4*)(h16 + (size_t)gn * HF + c4) = v;
    }
  }

  // Fused bucket histogram (LDS atomics only) on this block's edge chunk.
  {
    int ebeg = blockIdx.x * chunkE;
    int eend = min(ebeg + chunkE, n_edges);
    for (int e = ebeg + t; e < eend; e += 256)
      atomicAdd(&bhist[dst[e] >> BSHIFT], 1);
    __syncthreads();
    for (int k = t; k < nbuck; k += 256)
      bh[(size_t)k * gb + blockIdx.x] = bhist[k];
  }
}

// ---------------------------------------------------------------------------
// scanA: one block per bucket; parallel exclusive scan of bh[k][0..gb) ->
// sbase[k][b] and bucket total -> tot[k]. No fences, no global atomics.
// ---------------------------------------------------------------------------
__global__ __launch_bounds__(1024) void k_scanA(
    const int* __restrict__ bh, int* __restrict__ sbase, int* __restrict__ tot,
    int gb) {
  __shared__ int s[1024];
  int t = threadIdx.x, k = blockIdx.x;
  int v = (t < gb) ? bh[(size_t)k * gb + t] : 0;
  s[t] = v;
  __syncthreads();
  for (int off = 1; off < 1024; off <<= 1) {
    int u = (t >= off) ? s[t - off] : 0;
    __syncthreads();
    s[t] += u;
    __syncthreads();
  }
  if (t < gb) sbase[(size_t)k * gb + t] = s[t] - v;
  if (t == 1023) tot[k] = s[1023];
}

// ---------------------------------------------------------------------------
// scanB: single block; exclusive scan of bucket totals -> bucket_base.
// ---------------------------------------------------------------------------
__global__ __launch_bounds__(512) void k_scanB(
    const int* __restrict__ tot, int* __restrict__ bucket_base,
    int nbuck, int n_edges) {
  __shared__ int s[512];
  int t = threadIdx.x;
  int v = (t < nbuck) ? tot[t] : 0;
  s[t] = v;
  __syncthreads();
  for (int off = 1; off < 512; off <<= 1) {
    int u = (t >= off) ? s[t - off] : 0;
    __syncthreads();
    s[t] += u;
    __syncthreads();
  }
  if (t < nbuck) bucket_base[t] = s[t] - v;
  if (t == 0) bucket_base[nbuck] = n_edges;
}

// ---------------------------------------------------------------------------
// Partition: softmax alpha per edge, scatter one 16B record
// {src, d&127, alpha_lo, alpha_hi} to its bucket-exact slot. LDS cursors
// pre-reserved from bucket_base + sbase — ZERO global atomics.
// (Exact round-5 form: 1 edge/thread; int4 + swizzle variants regressed.)
// ---------------------------------------------------------------------------
__global__ __launch_bounds__(256) void k_part(
    const int* __restrict__ src, const int* __restrict__ dst,
    const float* __restrict__ e_src, const float* __restrict__ e_dst,
    const int* __restrict__ bucket_base, const int* __restrict__ sbase,
    uint4* __restrict__ recs, int nbuck, int chunkE, int n_edges, int gb) {
  __shared__ int cur[NBUCK_MAX];
  int t = threadIdx.x;
  for (int k = t; k < nbuck; k += 256)
    cur[k] = bucket_base[k] + sbase[(size_t)k * gb + blockIdx.x];
  __syncthreads();
  int beg = blockIdx.x * chunkE;
  int end = min(beg + chunkE, n_edges);
  for (int e = beg + t; e < end; e += 256) {
    int s = src[e], d = dst[e];
    float4 es = ((const float4*)e_src)[s];
    float4 ed = ((const float4*)e_dst)[d];
    float v0 = es.x + ed.x, v1 = es.y + ed.y, v2 = es.z + ed.z, v3 = es.w + ed.w;
    v0 = (v0 > 0.f) ? v0 : NEG_SLOPE * v0;
    v1 = (v1 > 0.f) ? v1 : NEG_SLOPE * v1;
    v2 = (v2 > 0.f) ? v2 : NEG_SLOPE * v2;
    v3 = (v3 > 0.f) ? v3 : NEG_SLOPE * v3;
    float m = fmaxf(fmaxf(v0, v1), fmaxf(v2, v3));
    float e0 = __expf(v0 - m), e1 = __expf(v1 - m);
    float e2 = __expf(v2 - m), e3 = __expf(v3 - m);
    float inv = 1.f / (e0 + e1 + e2 + e3);
    unsigned lo = (unsigned)f2b(e0 * inv) | ((unsigned)f2b(e1 * inv) << 16);
    unsigned hi = (unsigned)f2b(e2 * inv) | ((unsigned)f2b(e3 * inv) << 16);
    int pos = atomicAdd(&cur[d >> BSHIFT], 1);
    recs[pos] = make_uint4((unsigned)s, (unsigned)(d & (BNODES - 1)), lo, hi);
  }
}

// ---------------------------------------------------------------------------
// Aggregate (replaces k_sort + k_gather): one block per bucket, fp32
// accumulation tile [128 nodes][64 feats] in LDS with row stride 65 so
// ds_add_f32 banks decorrelate across nodes (~2-way, free per m136).
// 1024 thr = 16 waves; each wave handles 4 edges/iter (16 lanes/edge,
// lane = feature quad via one uint2 h16 load), unroll 4 -> 256 edges per
// block-iter, no serial reduction chain (rec -> h16 -> ds_add, all
// independent across the unroll). LDS atomics only. Records need no order.
// ---------------------------------------------------------------------------
__global__ __launch_bounds__(1024) void k_agg(
    const uint4* __restrict__ recs, const int* __restrict__ bucket_base,
    const unsigned short* __restrict__ h16, float* __restrict__ out,
    int n_nodes) {
  __shared__ float acc[BNODES * APAD];  // 33.3 KB
  const int t = threadIdx.x;
  const int k = blockIdx.x;
  for (int i = t; i < BNODES * APAD; i += 1024) acc[i] = 0.f;
  __syncthreads();
  const int beg = bucket_base[k];
  const int end = bucket_base[k + 1];
  const int w = t >> 6;          // wave 0..15
  const int lane = t & 63;
  const int p = lane >> 4;       // edge subgroup 0..3
  const int q = lane & 15;       // feature quad: features 4q..4q+3
  const unsigned sel = (unsigned)(q >> 2);       // head 0..3
  const unsigned shamt = (sel & 1u) * 16u;
  const uint2* h2 = (const uint2*)h16;           // 4 bf16 per uint2

  for (int j0 = beg + w * 16; j0 < end; j0 += 256) {
#pragma unroll
    for (int u = 0; u < 4; ++u) {
      int idx = j0 + u * 4 + p;
      int cidx = (idx < end) ? idx : (end - 1);
      uint4 r = recs[cidx];
      uint2 hv = h2[(size_t)r.x * (HF / 4) + q];
      unsigned wd = (sel & 2u) ? r.w : r.z;
      float al = __uint_as_float(((wd >> shamt) & 0xffffu) << 16);
      al = (idx < end) ? al : 0.f;
      float* arow = &acc[(int)r.y * APAD + 4 * q];
      atomicAdd(&arow[0], al * b2f((unsigned short)(hv.x & 0xffffu)));
      atomicAdd(&arow[1], al * b2f((unsigned short)(hv.x >> 16)));
      atomicAdd(&arow[2], al * b2f((unsigned short)(hv.y & 0xffffu)));
      atomicAdd(&arow[3], al * b2f((unsigned short)(hv.y >> 16)));
    }
  }
  __syncthreads();

  const int base_node = k << BSHIFT;
  float4* out4 = (float4*)out;
  for (int i = t; i < BNODES * (HF / 4); i += 1024) {
    int row = i >> 4, c4 = i & 15;
    int node = base_node + row;
    if (node < n_nodes) {
      const float* ar = &acc[row * APAD + c4 * 4];
      out4[(size_t)node * (HF / 4) + c4] =
          make_float4(ar[0], ar[1], ar[2], ar[3]);
    }
  }
}

extern "C" void kernel_launch(void* const* d_in, const int* in_sizes, int n_in,
                              void* d_out, int out_size, void* d_ws, size_t ws_size,
                              hipStream_t stream) {
  const float* x = (const float*)d_in[0];
  const int* ei = (const int*)d_in[1];
  const float* W = (const float*)d_in[2];
  const float* a = (const float*)d_in[3];
  float* out = (float*)d_out;

  const int n_nodes = in_sizes[0] / IN_FEAT;   // 50000
  const int n_edges = in_sizes[1] / 2;         // 800000
  const int* src = ei;
  const int* dst = ei + n_edges;

  const int nbuck = (n_nodes + BNODES - 1) >> BSHIFT;   // 391 (<= NBUCK_MAX)
  const int gb = (n_nodes + 63) / 64;                   // 782 (<= 1024 for scanA)
  const int chunkE = (n_edges + gb - 1) / gb;           // 1024

  char* ws = (char*)d_ws;
  size_t off = 0;
  uint4* recs = (uint4*)(ws + off);        off += (size_t)n_edges * 16;           // 12.8 MB
  unsigned short* h16 = (unsigned short*)(ws + off); off += (size_t)n_nodes * HF * 2; // 6.4 MB
  float* e_src = (float*)(ws + off);       off += (size_t)n_nodes * N_HEADS * 4;  // 0.8 MB
  float* e_dst = (float*)(ws + off);       off += (size_t)n_nodes * N_HEADS * 4;  // 0.8 MB
  int* bh = (int*)(ws + off);              off += (size_t)NBUCK_MAX * gb * 4;     // 1.6 MB
  int* sbase = (int*)(ws + off);           off += (size_t)NBUCK_MAX * gb * 4;     // 1.6 MB
  int* tot = (int*)(ws + off);             off += (size_t)NBUCK_MAX * 4;
  int* bucket_base = (int*)(ws + off);     off += (size_t)(NBUCK_MAX + 1) * 4;

  // Zero global atomics anywhere; no memsets; no device-scope fences.
  k_gemm<<<gb, 256, 0, stream>>>(x, W, a, h16, e_src, e_dst, dst, bh,
                                 n_nodes, n_edges, nbuck, chunkE, gb);
  k_scanA<<<nbuck, 1024, 0, stream>>>(bh, sbase, tot, gb);
  k_scanB<<<1, 512, 0, stream>>>(tot, bucket_base, nbuck, n_edges);
  k_part<<<gb, 256, 0, stream>>>(src, dst, e_src, e_dst, bucket_base, sbase,
                                 recs, nbuck, chunkE, n_edges, gb);
  k_agg<<<nbuck, 1024, 0, stream>>>(recs, bucket_base, h16, out, n_nodes);
}

// Round 10
// 166.980 us; speedup vs baseline: 2.8111x; 2.8111x over previous
//
#include <hip/hip_runtime.h>
#include <hip/hip_bf16.h>

#define IN_FEAT 128
#define N_HEADS 4
#define OUT_FEAT 16
#define HF 64  // N_HEADS * OUT_FEAT
#define NEG_SLOPE 0.2f

#define BSHIFT 7                 // 128 nodes per bucket
#define BNODES 128
#define NBUCK_MAX 512            // >= ceil(50000/128)=391
#define APAD 65                  // LDS acc row stride (64+1): (ry+f)%32 banks
#define FXSCALE 4194304.0f       // 2^22 fixed-point scale (range +-512, q ~2^-22)
#define FXINV (1.0f / 4194304.0f)

typedef __hip_bfloat16 bf16;
typedef __attribute__((ext_vector_type(8))) short short8;
typedef __attribute__((ext_vector_type(4))) float f32x4;

__device__ inline unsigned short f2b(float f) {
  bf16 b = __float2bfloat16(f);
  return *(unsigned short*)&b;
}
__device__ inline float b2f(unsigned short u) {
  return __uint_as_float((unsigned)u << 16);
}

// ---------------------------------------------------------------------------
// Kernel 1: h = x @ W via bf16 MFMA + fused LDS bucket histogram (no global
// atomics). Block = 256 thr = 4 waves = 64 nodes. (Round-5 exact.)
// ---------------------------------------------------------------------------
__global__ __launch_bounds__(256) void k_gemm(
    const float* __restrict__ x, const float* __restrict__ W,
    const float* __restrict__ a, unsigned short* __restrict__ h16,
    float* __restrict__ e_src, float* __restrict__ e_dst,
    const int* __restrict__ dst, int* __restrict__ bh,
    int n_nodes, int n_edges, int nbuck, int chunkE, int gb) {
  __shared__ unsigned short xs[64][136];
  __shared__ unsigned short wt[64][136];
  __shared__ unsigned short sh[64][68];
  __shared__ int bhist[NBUCK_MAX];
  const int t = threadIdx.x;
  const int nb = blockIdx.x * 64;
  const int lane = t & 63;
  const int w = t >> 6;

  for (int i = t; i < NBUCK_MAX; i += 256) bhist[i] = 0;

  const float4* x4 = (const float4*)x;
  for (int i = t; i < 64 * 32; i += 256) {
    int n = i >> 5, k4 = i & 31;
    int gn = nb + n;
    float4 v = (gn < n_nodes) ? x4[(size_t)gn * 32 + k4]
                              : make_float4(0.f, 0.f, 0.f, 0.f);
    ushort4 u;
    u.x = f2b(v.x); u.y = f2b(v.y); u.z = f2b(v.z); u.w = f2b(v.w);
    *(ushort4*)&xs[n][k4 * 4] = u;
  }
  for (int i = t; i < IN_FEAT * HF; i += 256) {
    int k = i >> 6, c = i & 63;
    wt[c][k] = f2b(W[i]);
  }
  __syncthreads();

  const int m = lane & 15;
  const int q = lane >> 4;
  f32x4 acc[4];
#pragma unroll
  for (int nt = 0; nt < 4; ++nt) acc[nt] = (f32x4){0.f, 0.f, 0.f, 0.f};

#pragma unroll
  for (int kc = 0; kc < 4; ++kc) {
    short8 af = *(const short8*)&xs[w * 16 + m][kc * 32 + q * 8];
#pragma unroll
    for (int nt = 0; nt < 4; ++nt) {
      short8 bfr = *(const short8*)&wt[nt * 16 + m][kc * 32 + q * 8];
      acc[nt] = __builtin_amdgcn_mfma_f32_16x16x32_bf16(af, bfr, acc[nt], 0, 0, 0);
    }
  }

#pragma unroll
  for (int nt = 0; nt < 4; ++nt)
#pragma unroll
    for (int r = 0; r < 4; ++r)
      sh[w * 16 + q * 4 + r][nt * 16 + m] = f2b(acc[nt][r]);
  __syncthreads();

  {
    int n = t >> 2, hd = t & 3;
    int gn = nb + n;
    if (gn < n_nodes) {
      float es = 0.f, ed = 0.f;
#pragma unroll
      for (int f = 0; f < OUT_FEAT; ++f) {
        float hv = b2f(sh[n][hd * 16 + f]);
        es = fmaf(hv, a[hd * 2 * OUT_FEAT + f], es);
        ed = fmaf(hv, a[hd * 2 * OUT_FEAT + OUT_FEAT + f], ed);
      }
      e_src[gn * N_HEADS + hd] = es;
      e_dst[gn * N_HEADS + hd] = ed;
    }
  }

  for (int i = t; i < 64 * 16; i += 256) {
    int n = i >> 4, c4 = (i & 15) * 4;
    int gn = nb + n;
    if (gn < n_nodes) {
      ushort4 v;
      v.x = sh[n][c4 + 0]; v.y = sh[n][c4 + 1];
      v.z = sh[n][c4 + 2]; v.w = sh[n][c4 + 3];
      *(ushort4*)(h16 + (size_t)gn * HF + c4) = v;
    }
  }

  // Fused bucket histogram (int LDS atomics only) on this block's edge chunk.
  {
    int ebeg = blockIdx.x * chunkE;
    int eend = min(ebeg + chunkE, n_edges);
    for (int e = ebeg + t; e < eend; e += 256)
      atomicAdd(&bhist[dst[e] >> BSHIFT], 1);
    __syncthreads();
    for (int k = t; k < nbuck; k += 256)
      bh[(size_t)k * gb + blockIdx.x] = bhist[k];
  }
}

// ---------------------------------------------------------------------------
// scanA: one block per bucket; parallel exclusive scan of bh[k][0..gb) ->
// sbase[k][b] and bucket total -> tot[k]. No fences, no global atomics.
// ---------------------------------------------------------------------------
__global__ __launch_bounds__(1024) void k_scanA(
    const int* __restrict__ bh, int* __restrict__ sbase, int* __restrict__ tot,
    int gb) {
  __shared__ int s[1024];
  int t = threadIdx.x, k = blockIdx.x;
  int v = (t < gb) ? bh[(size_t)k * gb + t] : 0;
  s[t] = v;
  __syncthreads();
  for (int off = 1; off < 1024; off <<= 1) {
    int u = (t >= off) ? s[t - off] : 0;
    __syncthreads();
    s[t] += u;
    __syncthreads();
  }
  if (t < gb) sbase[(size_t)k * gb + t] = s[t] - v;
  if (t == 1023) tot[k] = s[1023];
}

// ---------------------------------------------------------------------------
// scanB: single block; exclusive scan of bucket totals -> bucket_base.
// ---------------------------------------------------------------------------
__global__ __launch_bounds__(512) void k_scanB(
    const int* __restrict__ tot, int* __restrict__ bucket_base,
    int nbuck, int n_edges) {
  __shared__ int s[512];
  int t = threadIdx.x;
  int v = (t < nbuck) ? tot[t] : 0;
  s[t] = v;
  __syncthreads();
  for (int off = 1; off < 512; off <<= 1) {
    int u = (t >= off) ? s[t - off] : 0;
    __syncthreads();
    s[t] += u;
    __syncthreads();
  }
  if (t < nbuck) bucket_base[t] = s[t] - v;
  if (t == 0) bucket_base[nbuck] = n_edges;
}

// ---------------------------------------------------------------------------
// Partition: softmax alpha per edge, scatter one 16B record
// {src, d&127, alpha_lo, alpha_hi} to its bucket-exact slot. Int LDS cursors
// pre-reserved from bucket_base + sbase — ZERO global atomics. (R5 exact.)
// ---------------------------------------------------------------------------
__global__ __launch_bounds__(256) void k_part(
    const int* __restrict__ src, const int* __restrict__ dst,
    const float* __restrict__ e_src, const float* __restrict__ e_dst,
    const int* __restrict__ bucket_base, const int* __restrict__ sbase,
    uint4* __restrict__ recs, int nbuck, int chunkE, int n_edges, int gb) {
  __shared__ int cur[NBUCK_MAX];
  int t = threadIdx.x;
  for (int k = t; k < nbuck; k += 256)
    cur[k] = bucket_base[k] + sbase[(size_t)k * gb + blockIdx.x];
  __syncthreads();
  int beg = blockIdx.x * chunkE;
  int end = min(beg + chunkE, n_edges);
  for (int e = beg + t; e < end; e += 256) {
    int s = src[e], d = dst[e];
    float4 es = ((const float4*)e_src)[s];
    float4 ed = ((const float4*)e_dst)[d];
    float v0 = es.x + ed.x, v1 = es.y + ed.y, v2 = es.z + ed.z, v3 = es.w + ed.w;
    v0 = (v0 > 0.f) ? v0 : NEG_SLOPE * v0;
    v1 = (v1 > 0.f) ? v1 : NEG_SLOPE * v1;
    v2 = (v2 > 0.f) ? v2 : NEG_SLOPE * v2;
    v3 = (v3 > 0.f) ? v3 : NEG_SLOPE * v3;
    float m = fmaxf(fmaxf(v0, v1), fmaxf(v2, v3));
    float e0 = __expf(v0 - m), e1 = __expf(v1 - m);
    float e2 = __expf(v2 - m), e3 = __expf(v3 - m);
    float inv = 1.f / (e0 + e1 + e2 + e3);
    unsigned lo = (unsigned)f2b(e0 * inv) | ((unsigned)f2b(e1 * inv) << 16);
    unsigned hi = (unsigned)f2b(e2 * inv) | ((unsigned)f2b(e3 * inv) << 16);
    int pos = atomicAdd(&cur[d >> BSHIFT], 1);
    recs[pos] = make_uint4((unsigned)s, (unsigned)(d & (BNODES - 1)), lo, hi);
  }
}

// ---------------------------------------------------------------------------
// Aggregate (replaces k_sort + k_gather): one block per bucket, INT32
// fixed-point accumulation tile [128 nodes][64 feats] in LDS via native
// ds_add_u32 (float atomicAdd on LDS is a CAS loop -> 353µs, rounds 2&8).
// Round-5-proven edge layout: half-wave = edge parity, lane = feature pair
// (one uint h16 load = 128B/edge), unroll 8 -> 16 edges per independent
// batch. acc stride 65 ints -> (ry+2q+j)%32 banks ~2-way = free.
// 1024 thr = 16 waves; records need no order.
// ---------------------------------------------------------------------------
__global__ __launch_bounds__(1024) void k_agg(
    const uint4* __restrict__ recs, const int* __restrict__ bucket_base,
    const unsigned short* __restrict__ h16, float* __restrict__ out,
    int n_nodes) {
  __shared__ int acc[BNODES * APAD];  // 33.3 KB
  const int t = threadIdx.x;
  const int kb = blockIdx.x;
  for (int i = t; i < BNODES * APAD; i += 1024) acc[i] = 0;
  __syncthreads();
  const int beg = bucket_base[kb];
  const int end = bucket_base[kb + 1];
  const int w = t >> 6;              // wave 0..15
  const int lane = t & 63;
  const int half = lane >> 5;        // edge parity within pair
  const int q = lane & 31;           // feature pair: features 2q, 2q+1
  const unsigned sel = (unsigned)(q >> 3);   // head 0..3
  const unsigned shamt = (sel & 1u) * 16u;
  const unsigned* h32 = (const unsigned*)h16;  // 2 bf16 per uint

  for (int j0 = beg + w * 16; j0 < end; j0 += 256) {
#pragma unroll
    for (int u = 0; u < 8; ++u) {
      int idx = j0 + 2 * u + half;
      int cidx = (idx < end) ? idx : (end - 1);
      uint4 r = recs[cidx];
      unsigned hv = h32[(size_t)r.x * (HF / 2) + q];
      unsigned wd = (sel & 2u) ? r.w : r.z;
      float al = __uint_as_float(((wd >> shamt) & 0xffffu) << 16);
      al = (idx < end) ? al * FXSCALE : 0.f;
      int i0 = __float2int_rn(al * b2f((unsigned short)(hv & 0xffffu)));
      int i1 = __float2int_rn(al * b2f((unsigned short)(hv >> 16)));
      int* arow = &acc[(int)r.y * APAD + 2 * q];
      atomicAdd(&arow[0], i0);
      atomicAdd(&arow[1], i1);
    }
  }
  __syncthreads();

  const int base_node = kb << BSHIFT;
  float4* out4 = (float4*)out;
  for (int i = t; i < BNODES * (HF / 4); i += 1024) {
    int row = i >> 4, c4 = i & 15;
    int node = base_node + row;
    if (node < n_nodes) {
      const int* ar = &acc[row * APAD + c4 * 4];
      out4[(size_t)node * (HF / 4) + c4] =
          make_float4((float)ar[0] * FXINV, (float)ar[1] * FXINV,
                      (float)ar[2] * FXINV, (float)ar[3] * FXINV);
    }
  }
}

extern "C" void kernel_launch(void* const* d_in, const int* in_sizes, int n_in,
                              void* d_out, int out_size, void* d_ws, size_t ws_size,
                              hipStream_t stream) {
  const float* x = (const float*)d_in[0];
  const int* ei = (const int*)d_in[1];
  const float* W = (const float*)d_in[2];
  const float* a = (const float*)d_in[3];
  float* out = (float*)d_out;

  const int n_nodes = in_sizes[0] / IN_FEAT;   // 50000
  const int n_edges = in_sizes[1] / 2;         // 800000
  const int* src = ei;
  const int* dst = ei + n_edges;

  const int nbuck = (n_nodes + BNODES - 1) >> BSHIFT;   // 391 (<= NBUCK_MAX)
  const int gb = (n_nodes + 63) / 64;                   // 782 (<= 1024 for scanA)
  const int chunkE = (n_edges + gb - 1) / gb;           // 1024

  char* ws = (char*)d_ws;
  size_t off = 0;
  uint4* recs = (uint4*)(ws + off);        off += (size_t)n_edges * 16;           // 12.8 MB
  unsigned short* h16 = (unsigned short*)(ws + off); off += (size_t)n_nodes * HF * 2; // 6.4 MB
  float* e_src = (float*)(ws + off);       off += (size_t)n_nodes * N_HEADS * 4;  // 0.8 MB
  float* e_dst = (float*)(ws + off);       off += (size_t)n_nodes * N_HEADS * 4;  // 0.8 MB
  int* bh = (int*)(ws + off);              off += (size_t)NBUCK_MAX * gb * 4;     // 1.6 MB
  int* sbase = (int*)(ws + off);           off += (size_t)NBUCK_MAX * gb * 4;     // 1.6 MB
  int* tot = (int*)(ws + off);             off += (size_t)NBUCK_MAX * 4;
  int* bucket_base = (int*)(ws + off);     off += (size_t)(NBUCK_MAX + 1) * 4;

  // Zero global atomics; only INT LDS atomics (float LDS atomicAdd = CAS
  // loop on gfx950 — rounds 2 & 8 lesson). No memsets, no fences.
  k_gemm<<<gb, 256, 0, stream>>>(x, W, a, h16, e_src, e_dst, dst, bh,
                                 n_nodes, n_edges, nbuck, chunkE, gb);
  k_scanA<<<nbuck, 1024, 0, stream>>>(bh, sbase, tot, gb);
  k_scanB<<<1, 512, 0, stream>>>(tot, bucket_base, nbuck, n_edges);
  k_part<<<gb, 256, 0, stream>>>(src, dst, e_src, e_dst, bucket_base, sbase,
                                 recs, nbuck, chunkE, n_edges, gb);
  k_agg<<<nbuck, 1024, 0, stream>>>(recs, bucket_base, h16, out, n_nodes);
}